// Round 12
// baseline (108.717 us; speedup 1.0000x reference)
//
#include <hip/hip_runtime.h>
#include <math.h>

// Problem constants: B,F,C,H,W,D
constexpr int B_ = 2, F_ = 2, C_ = 64, H_ = 32, W_ = 104, D_ = 96;
constexpr int HW_ = H_ * W_;             // 3328
#define EPSF 1e-7f

// Workspace layout (floats):
//   lfT  [B,F,H,W,C]   channel-last lookup feats
//   curT [B,H,W,C]     channel-last current feats
constexpr size_t LFT_OFF  = 0;
constexpr size_t CURT_OFF = LFT_OFF + (size_t)B_ * F_ * HW_ * C_;   // 851968

constexpr int NT_BLKS = (HW_ / 32) * (C_ / 32) * (B_ * F_ + B_);  // 1248
constexpr int PXB   = 4;        // pixels per block — 16B stores + reuse sweet spot (R10: PXB=2 => 9x write amp)
constexpr int XT_   = W_ / PXB; // 26 x-tiles
constexpr int DPAD  = D_ + 1;   // 97: float4 row stride
constexpr int DPADI = D_ + 4;   // 100: int row stride

// DPP butterfly add over 16-lane group — bit-identical to __shfl_xor chain
// (only commutes IEEE add operands). VALU-only: no ds_swizzle latency.
template<int CTRL>
__device__ __forceinline__ float dpp_add(float x) {
    int y = __builtin_amdgcn_update_dpp(0, __float_as_int(x), CTRL, 0xf, 0xf, true);
    return x + __int_as_float(y);
}
__device__ __forceinline__ float group16_sum(float s) {
    s = dpp_add<0xB1>(s);    // quad_perm(1,0,3,2)  == + lane^1
    s = dpp_add<0x4E>(s);    // quad_perm(2,3,0,1)  == + lane^2
    s = dpp_add<0x141>(s);   // row_half_mirror     == + lane^4-equiv
    s = dpp_add<0x140>(s);   // row_mirror          == + lane^8-equiv
    return s;
}

// ---------------------------------------------------------------------------
// Prep: channel-last transpose [C, HW] -> [HW, C] for 6 slices (4 lf + 2 cur).
__global__ __launch_bounds__(256) void prep_kernel(
        const float* __restrict__ cur, const float* __restrict__ lf,
        float* __restrict__ ws) {
    __shared__ float tile[32][33];
    int bid = blockIdx.x;
    int slice = bid / 208;            // 208 = 104 n-blocks * 2 c-blocks
    int rem   = bid % 208;
    int nb = rem % 104, cb = rem / 104;
    const float* inS;
    float* outS;
    if (slice < B_ * F_) {
        inS  = lf + (size_t)slice * C_ * HW_;
        outS = ws + LFT_OFF + (size_t)slice * HW_ * C_;
    } else {
        int s2 = slice - B_ * F_;
        inS  = cur + (size_t)s2 * C_ * HW_;
        outS = ws + CURT_OFF + (size_t)s2 * HW_ * C_;
    }
    int t = threadIdx.x;
    int tx = t & 31, ty = t >> 5;
    int n0 = nb * 32, c0 = cb * 32;
    #pragma unroll
    for (int k = 0; k < 32; k += 8)
        tile[ty + k][tx] = inS[(size_t)(c0 + ty + k) * HW_ + n0 + tx];
    __syncthreads();
    #pragma unroll
    for (int k = 0; k < 32; k += 8)
        outS[(size_t)(n0 + ty + k) * C_ + c0 + tx] = tile[tx][ty + k];
}

// ---------------------------------------------------------------------------
// Mega kernel: block = (b, y, xt) covering 4 px * ALL 96 depths * 2 frames.
// 256 threads = 4 halves x (16 lanes x 4 px); each half walks 24 depths.
// Phase A: 768 projections -> LDS {offset, float4 weights}, contiguous in d.
// Phase B: straight-line unrolled d-walk; corner loads UNCONDITIONAL each
//          iteration (addr = max(off,0); masked -> zero weights kill the
//          garbage) so the compiler pipelines loads across iterations —
//          R9's dedup branch serialized on exposed L1 latency instead.
//          Channel reduce via DPP; cost via v_rcp (zero-preserving).
// Phase C: in-block missing-fill (cost==0 -> column max) + store.
__global__ __launch_bounds__(256, 6) void mega_kernel(
        const float* __restrict__ poses, const float* __restrict__ K,
        const float* __restrict__ invK, const float* __restrict__ depth_bins,
        const float* __restrict__ ws, float* __restrict__ out) {
    int t   = threadIdx.x;
    int bid = blockIdx.x;
    int xt  = bid % XT_;  int r = bid / XT_;
    int y   = r % H_;
    int b   = r / H_;

    if (y < 2 || y >= H_ - 2) {
        // whole row masked: cost column all-zero -> column max 0 -> output 0
        for (int k = t; k < PXB * D_; k += 256) {
            int d = k >> 2, px = k & 3;
            out[((size_t)(b * D_ + d) * H_ + y) * W_ + xt * PXB + px] = 0.0f;
        }
        return;   // block-uniform exit
    }

    __shared__ int    offsL[F_][PXB][DPADI];
    __shared__ float4 wtsL [F_][PXB][DPAD];
    __shared__ float  costb[PXB][DPAD];
    __shared__ float  pmax[32][PXB];
    __shared__ float  cmaxb[PXB];

    // ---- Phase A: projections (FP op order identical to R11) ----
    {
        // px = (t + 256k) & 3 = t & 3 — invariant across k. Hoist cam/interior.
        int pxA = t & 3;
        int xA  = xt * PXB + pxA;
        const float* iK = invK + (size_t)b * 16;
        float xf = (float)xA, yf = (float)y;
        float cam0 = __fmul_rn(iK[0], xf); cam0 = __fmaf_rn(iK[1], yf, cam0); cam0 = __fmaf_rn(iK[2],  1.0f, cam0);
        float cam1 = __fmul_rn(iK[4], xf); cam1 = __fmaf_rn(iK[5], yf, cam1); cam1 = __fmaf_rn(iK[6],  1.0f, cam1);
        float cam2 = __fmul_rn(iK[8], xf); cam2 = __fmaf_rn(iK[9], yf, cam2); cam2 = __fmaf_rn(iK[10], 1.0f, cam2);
        bool interior = (xA >= 2) && (xA <= W_ - 3);   // y already interior

        #pragma unroll
        for (int f = 0; f < F_; ++f) {
            const float* Kb   = K + (size_t)b * 16;
            const float* pose = poses + (size_t)(b * F_ + f) * 16;
            float P[12];
            #pragma unroll
            for (int i = 0; i < 3; ++i) {
                #pragma unroll
                for (int k = 0; k < 4; ++k) {
                    float acc = __fmul_rn(Kb[i*4+0], pose[0*4+k]);
                    acc = __fmaf_rn(Kb[i*4+1], pose[1*4+k], acc);
                    acc = __fmaf_rn(Kb[i*4+2], pose[2*4+k], acc);
                    acc = __fmaf_rn(Kb[i*4+3], pose[3*4+k], acc);
                    P[i*4+k] = acc;
                }
            }
            float vs = 0.f;
            #pragma unroll
            for (int j = 0; j < 16; ++j) vs += pose[j];
            bool valid = (vs != 0.f);

            #pragma unroll
            for (int k = 0; k < 2; ++k) {
                int idx = t + 256 * k;          // records [0,384) = dd*4 + px
                if (idx < PXB * D_) {
                    int dd = idx >> 2;
                    float depth = depth_bins[dd];
                    float p0 = __fmul_rn(depth, cam0);
                    float p1 = __fmul_rn(depth, cam1);
                    float p2 = __fmul_rn(depth, cam2);
                    float c0 = __fmul_rn(P[0], p0); c0 = __fmaf_rn(P[1], p1, c0); c0 = __fmaf_rn(P[2],  p2, c0); c0 = __fmaf_rn(P[3],  1.0f, c0);
                    float c1 = __fmul_rn(P[4], p0); c1 = __fmaf_rn(P[5], p1, c1); c1 = __fmaf_rn(P[6],  p2, c1); c1 = __fmaf_rn(P[7],  1.0f, c1);
                    float c2 = __fmul_rn(P[8], p0); c2 = __fmaf_rn(P[9], p1, c2); c2 = __fmaf_rn(P[10], p2, c2); c2 = __fmaf_rn(P[11], 1.0f, c2);
                    float denom = __fadd_rn(c2, EPSF);
                    float gx = c0 / denom;   // IEEE div — mask-critical
                    float gy = c1 / denom;
                    bool m = valid && interior && (gx >= 2.0f) && (gx <= (float)(W_ - 2))
                                               && (gy >= 2.0f) && (gy <= (float)(H_ - 2));
                    if (m) {
                        float x0f = floorf(gx), y0f = floorf(gy);
                        int   x0  = (int)x0f,   y0  = (int)y0f;
                        float wx1 = gx - x0f, wy1 = gy - y0f;
                        float wx0 = 1.f - wx1, wy0 = 1.f - wy1;
                        wtsL[f][pxA][dd] = make_float4(wy0 * wx0, wy0 * wx1,
                                                       wy1 * wx0, wy1 * wx1);
                        offsL[f][pxA][dd] = (y0 * W_ + x0) * C_;
                    } else {
                        offsL[f][pxA][dd] = -1;
                        // NaN-safety: weights MUST be finite (diff = s*0; 0*NaN=NaN).
                        wtsL[f][pxA][dd] = make_float4(0.f, 0.f, 0.f, 0.f);
                    }
                }
            }
        }
    }
    __syncthreads();

    // ---- Phase B: sampling; unconditional pipelined loads + DPP reduce ----
    {
        int lane = t & 15, px = (t >> 4) & 3, half = t >> 6;  // half in [0,4)
        int x = xt * PXB + px;
        const float4 cv = *(const float4*)(ws + CURT_OFF
                            + ((size_t)((b * H_ + y) * W_ + x)) * C_ + lane * 4);
        // two bases per frame: row y0 and row y0+1 (offsets 0 / +C_ fit imm)
        const float* lf0a = ws + LFT_OFF + (size_t)(b * F_ + 0) * HW_ * C_ + lane * 4;
        const float* lf0b = lf0a + W_ * C_;
        const float* lf1a = ws + LFT_OFF + (size_t)(b * F_ + 1) * HW_ * C_ + lane * 4;
        const float* lf1b = lf1a + W_ * C_;

        int dbeg = half * (D_ / 4);
        #pragma unroll 4
        for (int ki = 0; ki < D_ / 4; ++ki) {
            int dc = dbeg + ki;
            int    oc0 = offsL[0][px][dc], oc1 = offsL[1][px][dc];
            float4 wc0 = wtsL[0][px][dc],  wc1 = wtsL[1][px][dc];
            bool m0 = (oc0 >= 0), m1 = (oc1 >= 0);
            int a0 = oc0 >= 0 ? oc0 : 0;   // masked -> safe addr (w==0 kills it)
            int a1 = oc1 >= 0 ? oc1 : 0;

            // unconditional corner loads: no control dep -> compiler pipelines
            float4 q00 = *(const float4*)(lf0a + a0);
            float4 q01 = *(const float4*)(lf0a + a0 + C_);
            float4 q02 = *(const float4*)(lf0b + a0);
            float4 q03 = *(const float4*)(lf0b + a0 + C_);
            float4 q10 = *(const float4*)(lf1a + a1);
            float4 q11 = *(const float4*)(lf1a + a1 + C_);
            float4 q12 = *(const float4*)(lf1b + a1);
            float4 q13 = *(const float4*)(lf1b + a1 + C_);

            float costsum = 0.f, counts = 0.f;
            {
                float s;
                s  = fabsf(q00.x*wc0.x + q01.x*wc0.y + q02.x*wc0.z + q03.x*wc0.w - cv.x);
                s += fabsf(q00.y*wc0.x + q01.y*wc0.y + q02.y*wc0.z + q03.y*wc0.w - cv.y);
                s += fabsf(q00.z*wc0.x + q01.z*wc0.y + q02.z*wc0.z + q03.z*wc0.w - cv.z);
                s += fabsf(q00.w*wc0.x + q01.w*wc0.y + q02.w*wc0.z + q03.w*wc0.w - cv.w);
                s = group16_sum(s);
                float diff = __fmul_rn(s, 1.0f / 64.0f) * (m0 ? 1.0f : 0.0f);
                costsum += diff;
                counts  += (diff > 0.f) ? 1.0f : 0.0f;
            }
            {
                float s;
                s  = fabsf(q10.x*wc1.x + q11.x*wc1.y + q12.x*wc1.z + q13.x*wc1.w - cv.x);
                s += fabsf(q10.y*wc1.x + q11.y*wc1.y + q12.y*wc1.z + q13.y*wc1.w - cv.y);
                s += fabsf(q10.z*wc1.x + q11.z*wc1.y + q12.z*wc1.z + q13.z*wc1.w - cv.z);
                s += fabsf(q10.w*wc1.x + q11.w*wc1.y + q12.w*wc1.z + q13.w*wc1.w - cv.w);
                s = group16_sum(s);
                float diff = __fmul_rn(s, 1.0f / 64.0f) * (m1 ? 1.0f : 0.0f);
                costsum += diff;
                counts  += (diff > 0.f) ? 1.0f : 0.0f;
            }
            // cost via fast rcp: ~1e-7 rel err (bf16 threshold 2.9e-2), and
            // EXACT zero preserved (costsum==0 -> 0*rcp(eps)=0) so the ==0.0
            // missing-fill semantics are unchanged.
            float cost = costsum * __builtin_amdgcn_rcpf(__fadd_rn(counts, EPSF));
            if (lane == 0) costb[px][dc] = cost;
        }
    }
    __syncthreads();

    // ---- Phase C: missing-fill + store (first 128 threads own the data) ----
    {
        int j = t >> 2, px = t & 3;          // j in [0,64); only j<32 used
        float v[3];
        if (t < 128) {
            float pm = 0.f;
            #pragma unroll
            for (int k = 0; k < 3; ++k) {
                v[k] = costb[px][j + 32 * k];
                pm = fmaxf(pm, v[k]);
            }
            pmax[j][px] = pm;
        }
        __syncthreads();
        if (t < PXB) {
            float cm = 0.f;
            #pragma unroll
            for (int jj = 0; jj < 32; ++jj) cm = fmaxf(cm, pmax[jj][t]);
            cmaxb[t] = cm;
        }
        __syncthreads();
        if (t < 128) {
            float cm = cmaxb[px];
            int x = xt * PXB + px;
            #pragma unroll
            for (int k = 0; k < 3; ++k) {
                int d = j + 32 * k;
                out[((size_t)(b * D_ + d) * H_ + y) * W_ + x] = (v[k] == 0.0f) ? cm : v[k];
            }
        }
    }
}

// ---------------------------------------------------------------------------
extern "C" void kernel_launch(void* const* d_in, const int* in_sizes, int n_in,
                              void* d_out, int out_size, void* d_ws, size_t ws_size,
                              hipStream_t stream) {
    const float* cur        = (const float*)d_in[0];  // [B,C,H,W]
    const float* lf         = (const float*)d_in[1];  // [B,F,C,H,W]
    const float* poses      = (const float*)d_in[2];  // [B,F,4,4]
    const float* K          = (const float*)d_in[3];  // [B,4,4]
    const float* invK       = (const float*)d_in[4];  // [B,4,4]
    const float* depth_bins = (const float*)d_in[5];  // [D]
    float* out = (float*)d_out;
    float* ws  = (float*)d_ws;

    prep_kernel<<<NT_BLKS, 256, 0, stream>>>(cur, lf, ws);
    mega_kernel<<<B_ * H_ * XT_, 256, 0, stream>>>(poses, K, invK, depth_bins, ws, out);
}

// Round 14
// 95.980 us; speedup vs baseline: 1.1327x; 1.1327x over previous
//
#include <hip/hip_runtime.h>
#include <math.h>

// Problem constants: B,F,C,H,W,D
constexpr int B_ = 2, F_ = 2, C_ = 64, H_ = 32, W_ = 104, D_ = 96;
constexpr int HW_ = H_ * W_;             // 3328
#define EPSF 1e-7f

// Workspace layout (floats):
//   lfT  [B,F,H,W,C]   channel-last lookup feats
//   curT [B,H,W,C]     channel-last current feats
constexpr size_t LFT_OFF  = 0;
constexpr size_t CURT_OFF = LFT_OFF + (size_t)B_ * F_ * HW_ * C_;   // 851968

constexpr int NT_BLKS = (HW_ / 32) * (C_ / 32) * (B_ * F_ + B_);  // 1248
constexpr int PXB   = 4;        // pixels per block — 16B stores + reuse sweet spot (R10: PXB=2 => 9x write amp)
constexpr int XT_   = W_ / PXB; // 26 x-tiles
constexpr int DPAD  = D_ + 1;   // 97: float4 row stride
constexpr int DPADI = D_ + 4;   // 100: int row stride

// DPP butterfly add over 16-lane group — bit-identical to __shfl_xor chain
// (only commutes IEEE add operands). VALU-only: no ds_swizzle latency.
template<int CTRL>
__device__ __forceinline__ float dpp_add(float x) {
    int y = __builtin_amdgcn_update_dpp(0, __float_as_int(x), CTRL, 0xf, 0xf, true);
    return x + __int_as_float(y);
}
__device__ __forceinline__ float group16_sum(float s) {
    s = dpp_add<0xB1>(s);    // quad_perm(1,0,3,2)  == + lane^1
    s = dpp_add<0x4E>(s);    // quad_perm(2,3,0,1)  == + lane^2
    s = dpp_add<0x141>(s);   // row_half_mirror     == + lane^4-equiv
    s = dpp_add<0x140>(s);   // row_mirror          == + lane^8-equiv
    return s;
}

// ---------------------------------------------------------------------------
// Prep: channel-last transpose [C, HW] -> [HW, C] for 6 slices (4 lf + 2 cur).
__global__ __launch_bounds__(256) void prep_kernel(
        const float* __restrict__ cur, const float* __restrict__ lf,
        float* __restrict__ ws) {
    __shared__ float tile[32][33];
    int bid = blockIdx.x;
    int slice = bid / 208;            // 208 = 104 n-blocks * 2 c-blocks
    int rem   = bid % 208;
    int nb = rem % 104, cb = rem / 104;
    const float* inS;
    float* outS;
    if (slice < B_ * F_) {
        inS  = lf + (size_t)slice * C_ * HW_;
        outS = ws + LFT_OFF + (size_t)slice * HW_ * C_;
    } else {
        int s2 = slice - B_ * F_;
        inS  = cur + (size_t)s2 * C_ * HW_;
        outS = ws + CURT_OFF + (size_t)s2 * HW_ * C_;
    }
    int t = threadIdx.x;
    int tx = t & 31, ty = t >> 5;
    int n0 = nb * 32, c0 = cb * 32;
    #pragma unroll
    for (int k = 0; k < 32; k += 8)
        tile[ty + k][tx] = inS[(size_t)(c0 + ty + k) * HW_ + n0 + tx];
    __syncthreads();
    #pragma unroll
    for (int k = 0; k < 32; k += 8)
        outS[(size_t)(n0 + ty + k) * C_ + c0 + tx] = tile[tx][ty + k];
}

// ---------------------------------------------------------------------------
// Mega kernel: block = (b, y, xt) covering 4 px * ALL 96 depths * 2 frames.
// 256 threads = 4 halves x (16 lanes x 4 px); each half walks 24 depths.
// Phase A: 768 projections -> LDS {offset, float4 weights}, contiguous in d.
//          (cam/interior hoisted: px invariant across the k-loop)
// Phase B: unrolled d-walk; corner float4s cached in VGPRs keyed on offset
//          (dedup); channel reduce via DPP; cost via v_rcp (zero-preserving).
// Phase C: in-block missing-fill (cost==0 -> column max) + store.
__global__ __launch_bounds__(256, 6) void mega_kernel(
        const float* __restrict__ poses, const float* __restrict__ K,
        const float* __restrict__ invK, const float* __restrict__ depth_bins,
        const float* __restrict__ ws, float* __restrict__ out) {
    int t   = threadIdx.x;
    int bid = blockIdx.x;
    int xt  = bid % XT_;  int r = bid / XT_;
    int y   = r % H_;
    int b   = r / H_;

    if (y < 2 || y >= H_ - 2) {
        // whole row masked: cost column all-zero -> column max 0 -> output 0
        for (int k = t; k < PXB * D_; k += 256) {
            int d = k >> 2, px = k & 3;
            out[((size_t)(b * D_ + d) * H_ + y) * W_ + xt * PXB + px] = 0.0f;
        }
        return;   // block-uniform exit
    }

    __shared__ int    offsL[F_][PXB][DPADI];
    __shared__ float4 wtsL [F_][PXB][DPAD];
    __shared__ float  costb[PXB][DPAD];
    __shared__ float  pmax[32][PXB];
    __shared__ float  cmaxb[PXB];

    // ---- Phase A: projections (FP op order identical to R9/R11) ----
    {
        // px = (t + 256k) & 3 = t & 3 — invariant across k. Hoist cam/interior.
        int pxA = t & 3;
        int xA  = xt * PXB + pxA;
        const float* iK = invK + (size_t)b * 16;
        float xf = (float)xA, yf = (float)y;
        float cam0 = __fmul_rn(iK[0], xf); cam0 = __fmaf_rn(iK[1], yf, cam0); cam0 = __fmaf_rn(iK[2],  1.0f, cam0);
        float cam1 = __fmul_rn(iK[4], xf); cam1 = __fmaf_rn(iK[5], yf, cam1); cam1 = __fmaf_rn(iK[6],  1.0f, cam1);
        float cam2 = __fmul_rn(iK[8], xf); cam2 = __fmaf_rn(iK[9], yf, cam2); cam2 = __fmaf_rn(iK[10], 1.0f, cam2);
        bool interior = (xA >= 2) && (xA <= W_ - 3);   // y already interior

        #pragma unroll
        for (int f = 0; f < F_; ++f) {
            const float* Kb   = K + (size_t)b * 16;
            const float* pose = poses + (size_t)(b * F_ + f) * 16;
            float P[12];
            #pragma unroll
            for (int i = 0; i < 3; ++i) {
                #pragma unroll
                for (int k = 0; k < 4; ++k) {
                    float acc = __fmul_rn(Kb[i*4+0], pose[0*4+k]);
                    acc = __fmaf_rn(Kb[i*4+1], pose[1*4+k], acc);
                    acc = __fmaf_rn(Kb[i*4+2], pose[2*4+k], acc);
                    acc = __fmaf_rn(Kb[i*4+3], pose[3*4+k], acc);
                    P[i*4+k] = acc;
                }
            }
            float vs = 0.f;
            #pragma unroll
            for (int j = 0; j < 16; ++j) vs += pose[j];
            bool valid = (vs != 0.f);

            #pragma unroll
            for (int k = 0; k < 2; ++k) {
                int idx = t + 256 * k;          // records [0,384) = dd*4 + px
                if (idx < PXB * D_) {
                    int dd = idx >> 2;
                    float depth = depth_bins[dd];
                    float p0 = __fmul_rn(depth, cam0);
                    float p1 = __fmul_rn(depth, cam1);
                    float p2 = __fmul_rn(depth, cam2);
                    float c0 = __fmul_rn(P[0], p0); c0 = __fmaf_rn(P[1], p1, c0); c0 = __fmaf_rn(P[2],  p2, c0); c0 = __fmaf_rn(P[3],  1.0f, c0);
                    float c1 = __fmul_rn(P[4], p0); c1 = __fmaf_rn(P[5], p1, c1); c1 = __fmaf_rn(P[6],  p2, c1); c1 = __fmaf_rn(P[7],  1.0f, c1);
                    float c2 = __fmul_rn(P[8], p0); c2 = __fmaf_rn(P[9], p1, c2); c2 = __fmaf_rn(P[10], p2, c2); c2 = __fmaf_rn(P[11], 1.0f, c2);
                    float denom = __fadd_rn(c2, EPSF);
                    float gx = c0 / denom;   // IEEE div — mask-critical
                    float gy = c1 / denom;
                    bool m = valid && interior && (gx >= 2.0f) && (gx <= (float)(W_ - 2))
                                               && (gy >= 2.0f) && (gy <= (float)(H_ - 2));
                    if (m) {
                        float x0f = floorf(gx), y0f = floorf(gy);
                        int   x0  = (int)x0f,   y0  = (int)y0f;
                        float wx1 = gx - x0f, wy1 = gy - y0f;
                        float wx0 = 1.f - wx1, wy0 = 1.f - wy1;
                        wtsL[f][pxA][dd] = make_float4(wy0 * wx0, wy0 * wx1,
                                                       wy1 * wx0, wy1 * wx1);
                        offsL[f][pxA][dd] = (y0 * W_ + x0) * C_;
                    } else {
                        offsL[f][pxA][dd] = -1;
                        // NaN-safety: weights MUST be finite (diff = s*0; 0*NaN=NaN).
                        wtsL[f][pxA][dd] = make_float4(0.f, 0.f, 0.f, 0.f);
                    }
                }
            }
        }
    }
    __syncthreads();

    // ---- Phase B: sampling; VGPR corner cache + DPP channel reduce ----
    {
        int lane = t & 15, px = (t >> 4) & 3, half = t >> 6;  // half in [0,4)
        int x = xt * PXB + px;
        const float4 cv = *(const float4*)(ws + CURT_OFF
                            + ((size_t)((b * H_ + y) * W_ + x)) * C_ + lane * 4);
        // two bases per frame: row y0 and row y0+1 (offsets 0 / +C_ fit imm)
        const float* lf0a = ws + LFT_OFF + (size_t)(b * F_ + 0) * HW_ * C_ + lane * 4;
        const float* lf0b = lf0a + W_ * C_;
        const float* lf1a = ws + LFT_OFF + (size_t)(b * F_ + 1) * HW_ * C_ + lane * 4;
        const float* lf1b = lf1a + W_ * C_;

        float4 cc0[4], cc1[4];
        int oprev0 = -1, oprev1 = -1;
        #pragma unroll
        for (int k = 0; k < 4; ++k)
            cc0[k] = cc1[k] = make_float4(0.f, 0.f, 0.f, 0.f);

        int dbeg = half * (D_ / 4);
        #pragma unroll 4
        for (int ki = 0; ki < D_ / 4; ++ki) {
            int dc = dbeg + ki;
            int    oc0 = offsL[0][px][dc], oc1 = offsL[1][px][dc];
            float4 wc0 = wtsL[0][px][dc],  wc1 = wtsL[1][px][dc];

            float costsum = 0.f, counts = 0.f;
            // f = 0
            {
                bool m = (oc0 >= 0);
                if (m && oc0 != oprev0) {     // 16-lane-group-uniform branch
                    cc0[0] = *(const float4*)(lf0a + oc0);
                    cc0[1] = *(const float4*)(lf0a + oc0 + C_);
                    cc0[2] = *(const float4*)(lf0b + oc0);
                    cc0[3] = *(const float4*)(lf0b + oc0 + C_);
                    oprev0 = oc0;
                }
                float s;
                s  = fabsf(cc0[0].x*wc0.x + cc0[1].x*wc0.y + cc0[2].x*wc0.z + cc0[3].x*wc0.w - cv.x);
                s += fabsf(cc0[0].y*wc0.x + cc0[1].y*wc0.y + cc0[2].y*wc0.z + cc0[3].y*wc0.w - cv.y);
                s += fabsf(cc0[0].z*wc0.x + cc0[1].z*wc0.y + cc0[2].z*wc0.z + cc0[3].z*wc0.w - cv.z);
                s += fabsf(cc0[0].w*wc0.x + cc0[1].w*wc0.y + cc0[2].w*wc0.z + cc0[3].w*wc0.w - cv.w);
                s = group16_sum(s);
                float diff = __fmul_rn(s, 1.0f / 64.0f) * (m ? 1.0f : 0.0f);
                costsum += diff;
                counts  += (diff > 0.f) ? 1.0f : 0.0f;
            }
            // f = 1
            {
                bool m = (oc1 >= 0);
                if (m && oc1 != oprev1) {
                    cc1[0] = *(const float4*)(lf1a + oc1);
                    cc1[1] = *(const float4*)(lf1a + oc1 + C_);
                    cc1[2] = *(const float4*)(lf1b + oc1);
                    cc1[3] = *(const float4*)(lf1b + oc1 + C_);
                    oprev1 = oc1;
                }
                float s;
                s  = fabsf(cc1[0].x*wc1.x + cc1[1].x*wc1.y + cc1[2].x*wc1.z + cc1[3].x*wc1.w - cv.x);
                s += fabsf(cc1[0].y*wc1.x + cc1[1].y*wc1.y + cc1[2].y*wc1.z + cc1[3].y*wc1.w - cv.y);
                s += fabsf(cc1[0].z*wc1.x + cc1[1].z*wc1.y + cc1[2].z*wc1.z + cc1[3].z*wc1.w - cv.z);
                s += fabsf(cc1[0].w*wc1.x + cc1[1].w*wc1.y + cc1[2].w*wc1.z + cc1[3].w*wc1.w - cv.w);
                s = group16_sum(s);
                float diff = __fmul_rn(s, 1.0f / 64.0f) * (m ? 1.0f : 0.0f);
                costsum += diff;
                counts  += (diff > 0.f) ? 1.0f : 0.0f;
            }
            // cost via fast rcp: ~1e-7 rel err (bf16 threshold 2.9e-2), and
            // EXACT zero preserved (costsum==0 -> 0*rcp(eps)=0) so the ==0.0
            // missing-fill semantics are unchanged.
            float cost = costsum * __builtin_amdgcn_rcpf(__fadd_rn(counts, EPSF));
            if (lane == 0) costb[px][dc] = cost;
        }
    }
    __syncthreads();

    // ---- Phase C: missing-fill + store (first 128 threads own the data) ----
    {
        int j = t >> 2, px = t & 3;          // j in [0,64); only j<32 used
        float v[3];
        if (t < 128) {
            float pm = 0.f;
            #pragma unroll
            for (int k = 0; k < 3; ++k) {
                v[k] = costb[px][j + 32 * k];
                pm = fmaxf(pm, v[k]);
            }
            pmax[j][px] = pm;
        }
        __syncthreads();
        if (t < PXB) {
            float cm = 0.f;
            #pragma unroll
            for (int jj = 0; jj < 32; ++jj) cm = fmaxf(cm, pmax[jj][t]);
            cmaxb[t] = cm;
        }
        __syncthreads();
        if (t < 128) {
            float cm = cmaxb[px];
            int x = xt * PXB + px;
            #pragma unroll
            for (int k = 0; k < 3; ++k) {
                int d = j + 32 * k;
                out[((size_t)(b * D_ + d) * H_ + y) * W_ + x] = (v[k] == 0.0f) ? cm : v[k];
            }
        }
    }
}

// ---------------------------------------------------------------------------
extern "C" void kernel_launch(void* const* d_in, const int* in_sizes, int n_in,
                              void* d_out, int out_size, void* d_ws, size_t ws_size,
                              hipStream_t stream) {
    const float* cur        = (const float*)d_in[0];  // [B,C,H,W]
    const float* lf         = (const float*)d_in[1];  // [B,F,C,H,W]
    const float* poses      = (const float*)d_in[2];  // [B,F,4,4]
    const float* K          = (const float*)d_in[3];  // [B,4,4]
    const float* invK       = (const float*)d_in[4];  // [B,4,4]
    const float* depth_bins = (const float*)d_in[5];  // [D]
    float* out = (float*)d_out;
    float* ws  = (float*)d_ws;

    prep_kernel<<<NT_BLKS, 256, 0, stream>>>(cur, lf, ws);
    mega_kernel<<<B_ * H_ * XT_, 256, 0, stream>>>(poses, K, invK, depth_bins, ws, out);
}